// Round 1
// baseline (7003.392 us; speedup 1.0000x reference)
//
#include <hip/hip_runtime.h>

// ConsciousTransformer forward, fp32 correctness-first implementation.
// Dims: C=512, V=32000, L=2, P=2, E=8, HM=1024, H=8, M=256, B=2, T=1024, N=B*T=2048
// Workspace requirement: 27 * 2048*512 floats = ~113 MB.

#define NTOK 2048
#define CDIM 512
#define TLEN 1024
#define NB 2
#define NH 8
#define HD 64
#define VDIM 32000

// ---------------- generic fp32 GEMM: C = res + alpha*act(A@B + bias) ----------------
// A [M,K] row-major (lda), B [K,N] row-major (or [N,K] if transB), C [M,N] (ldc).
// act: 0=none, 1=silu, 2=tanh. All M,N multiples of 64; K multiple of 16.
__global__ __launch_bounds__(256) void gemm_f32(
    const float* __restrict__ A, int lda,
    const float* __restrict__ B,
    float* __restrict__ C_, int ldc,
    const float* __restrict__ bias,
    const float* __restrict__ res, int ldres, float alpha,
    int M, int Nn, int K, int transB, int act)
{
    __shared__ float As[16][65];
    __shared__ float Bs[16][68];
    const int tid = threadIdx.x;
    const int tx = tid & 15, ty = tid >> 4;
    const int m0 = blockIdx.y * 64, n0 = blockIdx.x * 64;
    float acc[4][4] = {{0.f}};
    const int aRow = tid >> 2;
    const int aCol = (tid & 3) * 4;
    for (int k0 = 0; k0 < K; k0 += 16) {
        float4 av = *(const float4*)(A + (long)(m0 + aRow) * lda + (k0 + aCol));
        As[aCol + 0][aRow] = av.x;
        As[aCol + 1][aRow] = av.y;
        As[aCol + 2][aRow] = av.z;
        As[aCol + 3][aRow] = av.w;
        if (!transB) {
            const int kk = tid >> 4;
            const int nb = (tid & 15) * 4;
            float4 bv = *(const float4*)(B + (long)(k0 + kk) * Nn + (n0 + nb));
            *(float4*)&Bs[kk][nb] = bv;
        } else {
            const int nr = tid >> 2;
            const int kb = (tid & 3) * 4;
            float4 bv = *(const float4*)(B + (long)(n0 + nr) * K + (k0 + kb));
            Bs[kb + 0][nr] = bv.x;
            Bs[kb + 1][nr] = bv.y;
            Bs[kb + 2][nr] = bv.z;
            Bs[kb + 3][nr] = bv.w;
        }
        __syncthreads();
#pragma unroll
        for (int kk = 0; kk < 16; ++kk) {
            float a[4], b[4];
#pragma unroll
            for (int i = 0; i < 4; ++i) a[i] = As[kk][ty + 16 * i];
#pragma unroll
            for (int j = 0; j < 4; ++j) b[j] = Bs[kk][tx + 16 * j];
#pragma unroll
            for (int i = 0; i < 4; ++i)
#pragma unroll
                for (int j = 0; j < 4; ++j)
                    acc[i][j] += a[i] * b[j];
        }
        __syncthreads();
    }
#pragma unroll
    for (int i = 0; i < 4; ++i) {
        const int m = m0 + ty + 16 * i;
#pragma unroll
        for (int j = 0; j < 4; ++j) {
            const int n = n0 + tx + 16 * j;
            float v = acc[i][j];
            if (bias) v += bias[n];
            if (act == 1) v = v / (1.f + __expf(-v));          // silu
            else if (act == 2) v = tanhf(v);
            v *= alpha;
            if (res) v += res[(long)m * ldres + n];
            C_[(long)m * ldc + n] = v;
        }
    }
}

// ---------------- embedding gather ----------------
__global__ __launch_bounds__(256) void embed_k(const int* __restrict__ ids,
                                               const float* __restrict__ ew,
                                               float* __restrict__ x)
{
    const int n = blockIdx.x, t = threadIdx.x;
    const long r = (long)ids[n] * CDIM;
    x[(long)n * CDIM + t]       = ew[r + t];
    x[(long)n * CDIM + 256 + t] = ew[r + 256 + t];
}

// ---------------- row softmax (width 256), in place ----------------
__global__ __launch_bounds__(256) void smrows_k(float* __restrict__ a)
{
    const int n = blockIdx.x, t = threadIdx.x;
    __shared__ float rs[256];
    float v = a[(long)n * 256 + t];
    rs[t] = v; __syncthreads();
    for (int o = 128; o; o >>= 1) { if (t < o) rs[t] = fmaxf(rs[t], rs[t + o]); __syncthreads(); }
    const float m = rs[0]; __syncthreads();
    const float e = __expf(v - m);
    rs[t] = e; __syncthreads();
    for (int o = 128; o; o >>= 1) { if (t < o) rs[t] += rs[t + o]; __syncthreads(); }
    a[(long)n * 256 + t] = e / rs[0];
}

// ---------------- concat two [N,C] -> [N,2C] ----------------
__global__ __launch_bounds__(256) void concat_k(const float* __restrict__ a,
                                                const float* __restrict__ b,
                                                float* __restrict__ o)
{
    const long i = (long)blockIdx.x * 256 + threadIdx.x; // over N*C
    const long n = i >> 9;
    const int c = (int)(i & 511);
    o[n * 1024 + c]       = a[i];
    o[n * 1024 + 512 + c] = b[i];
}

// ---------------- mean over T (partial + reduce) ----------------
__global__ __launch_bounds__(64) void meanp_k(const float* __restrict__ A, int lda,
                                              float* __restrict__ part)
{
    const int bid = blockIdx.x;           // 256 blocks: 16 tslice x 8 cgroup x 2 batch
    const int ts = bid & 15;
    const int cg = (bid >> 4) & 7;
    const int b  = bid >> 7;
    const int c  = cg * 64 + threadIdx.x;
    const float* p = A + ((long)b * TLEN + ts * 64) * lda + c;
    float s = 0.f;
    for (int t = 0; t < 64; ++t) s += p[(long)t * lda];
    part[(long)ts * 1024 + b * 512 + c] = s;
}
__global__ __launch_bounds__(256) void meanr_k(const float* __restrict__ part,
                                               float* __restrict__ hm)
{
    const int i = blockIdx.x * 256 + threadIdx.x; // 0..1023
    float s = 0.f;
    for (int ts = 0; ts < 16; ++ts) s += part[ts * 1024 + i];
    hm[i] = s * (1.f / 1024.f);
}

// ---------------- awareness: [B,C] @ aw_w[lp] + aw_b -> [B,H] ----------------
__global__ __launch_bounds__(64) void aware_k(const float* __restrict__ hm,
                                              const float* __restrict__ aw_w,
                                              const float* __restrict__ aw_b,
                                              int lp, float* __restrict__ out)
{
    const int t = threadIdx.x;
    if (t < NB * NH) {
        const int b = t >> 3, hh = t & 7;
        const float* W = aw_w + (long)lp * CDIM * NH;
        const float* x = hm + b * CDIM;
        float s = aw_b[lp * NH + hh];
        for (int c = 0; c < CDIM; ++c) s += x[c] * W[c * NH + hh];
        out[t] = s;
    }
}

// ---------------- fused attention (8 rows per block) ----------------
// scores -> softmax -> (+0.3*prior) -> write prior -> P@V -> silu -> outs
__global__ __launch_bounds__(256) void attn_k(
    const float* __restrict__ qkv,     // [N, 3*C] as [n][i*C + h*64 + d]
    const float* __restrict__ dscale, int lp,
    const float* __restrict__ aware,   // [B*H]
    float* __restrict__ prior,         // [B,H,T,T]
    int use_prior,
    float* __restrict__ outs, int ldouts, int out_off)
{
    const int tid = threadIdx.x;
    const int rblk = blockIdx.x % (TLEN / 8);
    const int bh = blockIdx.x / (TLEN / 8);
    const int b = bh / NH, h = bh % NH;
    const int t0 = rblk * 8;
    __shared__ float qs[8][64];
    __shared__ float kt[64][68];
    __shared__ float ss[8][1024];
    __shared__ float rinv[8];
    const float scale = dscale[lp] * aware[bh];
    for (int i = tid; i < 512; i += 256) {
        const int r = i >> 6, d = i & 63;
        qs[r][d] = qkv[(long)(b * TLEN + t0 + r) * 1536 + h * 64 + d] * scale;
    }
    __syncthreads();
    // scores
    for (int s0 = 0; s0 < TLEN; s0 += 64) {
        for (int i = tid; i < 4096; i += 256) {
            const int sr = i >> 6, d = i & 63;
            kt[sr][d] = qkv[(long)(b * TLEN + s0 + sr) * 1536 + 512 + h * 64 + d];
        }
        __syncthreads();
        for (int i = tid; i < 512; i += 256) {
            const int r = i >> 6, c = i & 63;
            float acc = 0.f;
#pragma unroll
            for (int d = 0; d < 64; d += 4) {
                const float4 qv = *(const float4*)&qs[r][d];
                const float4 kv = *(const float4*)&kt[c][d];
                acc += qv.x * kv.x + qv.y * kv.y + qv.z * kv.z + qv.w * kv.w;
            }
            ss[r][s0 + c] = acc;
        }
        __syncthreads();
    }
    // softmax per row: 32 lanes per row
    {
        const int r = tid >> 5, lane = tid & 31;
        float m = -1e30f;
        for (int c = lane; c < TLEN; c += 32) m = fmaxf(m, ss[r][c]);
        for (int o = 16; o; o >>= 1) m = fmaxf(m, __shfl_down(m, o, 32));
        m = __shfl(m, 0, 32);
        float sum = 0.f;
        for (int c = lane; c < TLEN; c += 32) {
            const float e = __expf(ss[r][c] - m);
            ss[r][c] = e;
            sum += e;
        }
        for (int o = 16; o; o >>= 1) sum += __shfl_down(sum, o, 32);
        if (lane == 0) rinv[r] = 1.f / sum;
    }
    __syncthreads();
    // normalize, add prior, store attn to prior
    {
        const long pbase = ((long)bh * TLEN + t0) * TLEN;
        for (int i = tid; i < 8 * TLEN; i += 256) {
            const int r = i >> 10, c = i & 1023;
            float v = ss[r][c] * rinv[r];
            if (use_prior) v += 0.3f * prior[pbase + (long)r * TLEN + c];
            ss[r][c] = v;
            prior[pbase + (long)r * TLEN + c] = v;
        }
    }
    __syncthreads();
    // o = attn @ V, then silu, write
    float oacc0 = 0.f, oacc1 = 0.f;
    for (int s0 = 0; s0 < TLEN; s0 += 64) {
        for (int i = tid; i < 4096; i += 256) {
            const int sr = i >> 6, d = i & 63;
            kt[sr][d] = qkv[(long)(b * TLEN + s0 + sr) * 1536 + 1024 + h * 64 + d];
        }
        __syncthreads();
        {
            const int r0 = tid >> 6, d0 = tid & 63;
            const int r1 = (tid + 256) >> 6, d1 = (tid + 256) & 63;
            float a0 = 0.f, a1 = 0.f;
#pragma unroll
            for (int sr = 0; sr < 64; ++sr) {
                a0 += ss[r0][s0 + sr] * kt[sr][d0];
                a1 += ss[r1][s0 + sr] * kt[sr][d1];
            }
            oacc0 += a0; oacc1 += a1;
        }
        __syncthreads();
    }
    {
        const int r0 = tid >> 6, d0 = tid & 63;
        const int r1 = (tid + 256) >> 6, d1 = (tid + 256) & 63;
        float v0 = oacc0 / (1.f + __expf(-oacc0));
        float v1 = oacc1 / (1.f + __expf(-oacc1));
        outs[(long)(b * TLEN + t0 + r0) * ldouts + out_off + h * 64 + d0] = v0;
        outs[(long)(b * TLEN + t0 + r1) * ldouts + out_off + h * 64 + d1] = v1;
    }
}

// ---------------- layernorm over C=512 ----------------
__global__ __launch_bounds__(256) void ln_k(const float* __restrict__ z,
                                            const float* __restrict__ g,
                                            const float* __restrict__ bb,
                                            float* __restrict__ xn)
{
    const int n = blockIdx.x, t = threadIdx.x;
    __shared__ float rs[256], rq[256];
    const float v0 = z[(long)n * 512 + t];
    const float v1 = z[(long)n * 512 + 256 + t];
    rs[t] = v0 + v1;
    rq[t] = v0 * v0 + v1 * v1;
    __syncthreads();
    for (int o = 128; o; o >>= 1) {
        if (t < o) { rs[t] += rs[t + o]; rq[t] += rq[t + o]; }
        __syncthreads();
    }
    const float mu = rs[0] * (1.f / 512.f);
    const float var = rq[0] * (1.f / 512.f) - mu * mu;
    const float rstd = rsqrtf(var + 1e-5f);
    xn[(long)n * 512 + t]       = (v0 - mu) * rstd * g[t] + bb[t];
    xn[(long)n * 512 + 256 + t] = (v1 - mu) * rstd * g[t + 256] + bb[t + 256];
}

// ---------------- MoE gate: softmax over E=8, top-2 ----------------
__global__ __launch_bounds__(64) void gate_k(const float* __restrict__ xn,
                                             const float* __restrict__ gw,
                                             const float* __restrict__ gb,
                                             int l, float* __restrict__ wv,
                                             int* __restrict__ eidx)
{
    const int n = blockIdx.x, t = threadIdx.x;
    const int e = t & 7, ch = t >> 3;
    const float* W = gw + (long)l * CDIM * 8;
    float part = 0.f;
    for (int k = ch * 64; k < ch * 64 + 64; ++k) part += xn[(long)n * CDIM + k] * W[k * 8 + e];
    part += __shfl_xor(part, 8, 64);
    part += __shfl_xor(part, 16, 64);
    part += __shfl_xor(part, 32, 64);
    __shared__ float lg[8];
    if (t < 8) lg[t] = part + gb[l * 8 + t];
    __syncthreads();
    if (t == 0) {
        float m = lg[0];
        for (int i = 1; i < 8; ++i) m = fmaxf(m, lg[i]);
        float p[8], s = 0.f;
        for (int i = 0; i < 8; ++i) { p[i] = __expf(lg[i] - m); s += p[i]; }
        const float inv = 1.f / s;
        int i0 = 0;
        for (int i = 1; i < 8; ++i) if (p[i] > p[i0]) i0 = i;
        int i1 = (i0 == 0) ? 1 : 0;
        for (int i = 0; i < 8; ++i) { if (i == i0) continue; if (p[i] > p[i1]) i1 = i; }
        eidx[n * 2] = i0; eidx[n * 2 + 1] = i1;
        wv[n * 2] = p[i0] * inv; wv[n * 2 + 1] = p[i1] * inv;
    }
}

// ---------------- MoE expert mlp1 (+ x*silu(x) act): per (token,slot) ----------------
__global__ __launch_bounds__(256) void moe_eh_k(const float* __restrict__ xn,
                                                const int* __restrict__ eidx,
                                                const float* __restrict__ ew1,
                                                const float* __restrict__ eb1,
                                                int l, float* __restrict__ eh)
{
    const int ns = blockIdx.x, n = ns >> 1, slot = ns & 1;
    const int e = eidx[n * 2 + slot];
    const float* W = ew1 + (long)(l * 8 + e) * CDIM * 1024;
    const float* bb = eb1 + (long)(l * 8 + e) * 1024;
    __shared__ float xs[CDIM];
    const int t = threadIdx.x;
    xs[t] = xn[(long)n * CDIM + t];
    xs[t + 256] = xn[(long)n * CDIM + 256 + t];
    __syncthreads();
    float acc[4];
#pragma unroll
    for (int j = 0; j < 4; ++j) acc[j] = bb[t + 256 * j];
    for (int k = 0; k < CDIM; ++k) {
        const float xv = xs[k];
        const float* Wr = W + (long)k * 1024;
#pragma unroll
        for (int j = 0; j < 4; ++j) acc[j] += xv * Wr[t + 256 * j];
    }
#pragma unroll
    for (int j = 0; j < 4; ++j) {
        const float a = acc[j];
        eh[(long)ns * 1024 + t + 256 * j] = a * a / (1.f + __expf(-a)); // a*silu(a)
    }
}

// ---------------- MoE expert mlp2: per (token,slot) ----------------
__global__ __launch_bounds__(256) void moe_ey_k(const float* __restrict__ eh,
                                                const int* __restrict__ eidx,
                                                const float* __restrict__ ew2,
                                                const float* __restrict__ eb2,
                                                int l, float* __restrict__ ey)
{
    const int ns = blockIdx.x, n = ns >> 1, slot = ns & 1;
    const int e = eidx[n * 2 + slot];
    const float* W = ew2 + (long)(l * 8 + e) * 1024 * CDIM;
    const float* bb = eb2 + (long)(l * 8 + e) * CDIM;
    __shared__ float xs[1024];
    const int t = threadIdx.x;
    for (int i = t; i < 1024; i += 256) xs[i] = eh[(long)ns * 1024 + i];
    __syncthreads();
    float a0 = bb[t], a1 = bb[t + 256];
    for (int k = 0; k < 1024; ++k) {
        const float xv = xs[k];
        a0 += xv * W[(long)k * CDIM + t];
        a1 += xv * W[(long)k * CDIM + t + 256];
    }
    ey[(long)ns * CDIM + t] = a0;
    ey[(long)ns * CDIM + t + 256] = a1;
}

// ---------------- reason = xn + 0.5*(w0*ey0 + w1*ey1) ----------------
__global__ __launch_bounds__(256) void reason_k(const float* __restrict__ xn,
                                                const float* __restrict__ ey,
                                                const float* __restrict__ wv,
                                                float* __restrict__ reason)
{
    const long i = (long)blockIdx.x * 256 + threadIdx.x;
    const long n = i >> 9;
    const int c = (int)(i & 511);
    const float v = wv[n * 2] * ey[n * 1024 + c] + wv[n * 2 + 1] * ey[n * 1024 + 512 + c];
    reason[i] = xn[i] + 0.5f * v;
}

// ---------------- quality = sigmoid(t1 . q2w + q2b) per token ----------------
__global__ __launch_bounds__(256) void qual_k(const float* __restrict__ t1,
                                              const float* __restrict__ q2w,
                                              const float* __restrict__ q2b,
                                              int l, float* __restrict__ qual)
{
    const int n = blockIdx.x, t = threadIdx.x;
    const float* W = q2w + (long)l * 2048;
    float s = 0.f;
    for (int k = t; k < 2048; k += 256) s += t1[(long)n * 2048 + k] * W[k];
    __shared__ float rs[256];
    rs[t] = s; __syncthreads();
    for (int o = 128; o; o >>= 1) { if (t < o) rs[t] += rs[t + o]; __syncthreads(); }
    if (t == 0) {
        const float q = rs[0] + q2b[l];
        qual[n] = 1.f / (1.f + __expf(-q));
    }
}

// ---------------- xq = x_in * (1 - quality) ----------------
__global__ __launch_bounds__(256) void xq_k(const float* __restrict__ x_in,
                                            const float* __restrict__ qual,
                                            float* __restrict__ xq)
{
    const long i = (long)blockIdx.x * 256 + threadIdx.x;
    const long n = i >> 9;
    xq[i] = x_in[i] * (1.f - qual[n]);
}

// ---------------- x = reason + gate*pscale*intro ----------------
__global__ __launch_bounds__(256) void final_k(const float* __restrict__ reason,
                                               const float* __restrict__ gate,
                                               const float* __restrict__ pscale,
                                               const float* __restrict__ intro,
                                               float* __restrict__ xo)
{
    const long i = (long)blockIdx.x * 256 + threadIdx.x;
    const int c = (int)(i & 511);
    xo[i] = reason[i] + gate[i] * pscale[c] * intro[i];
}

// =======================================================================
extern "C" void kernel_launch(void* const* d_in, const int* in_sizes, int n_in,
                              void* d_out, int out_size, void* d_ws, size_t ws_size,
                              hipStream_t stream)
{
    (void)in_sizes; (void)n_in; (void)out_size; (void)ws_size;
    const int*   ids     = (const int*)  d_in[0];
    const float* embed_w = (const float*)d_in[1];
    const float* mem     = (const float*)d_in[2];
    const float* mp_w    = (const float*)d_in[3];
    const float* mp_b    = (const float*)d_in[4];
    const float* qkv_w   = (const float*)d_in[5];
    const float* qkv_b   = (const float*)d_in[6];
    const float* aw_w    = (const float*)d_in[7];
    const float* aw_b    = (const float*)d_in[8];
    const float* dscale  = (const float*)d_in[9];
    const float* mg_w    = (const float*)d_in[10];
    const float* mg_b    = (const float*)d_in[11];
    const float* ln_g    = (const float*)d_in[12];
    const float* ln_b    = (const float*)d_in[13];
    const float* gw      = (const float*)d_in[14];
    const float* gb      = (const float*)d_in[15];
    const float* ew1     = (const float*)d_in[16];
    const float* eb1     = (const float*)d_in[17];
    const float* ew2     = (const float*)d_in[18];
    const float* eb2     = (const float*)d_in[19];
    const float* q1w     = (const float*)d_in[20];
    const float* q1b     = (const float*)d_in[21];
    const float* q2w     = (const float*)d_in[22];
    const float* q2b     = (const float*)d_in[23];
    const float* errw    = (const float*)d_in[24];
    const float* errb    = (const float*)d_in[25];
    const float* ag1w    = (const float*)d_in[26];
    const float* ag1b    = (const float*)d_in[27];
    const float* ag2w    = (const float*)d_in[28];
    const float* ag2b    = (const float*)d_in[29];
    const float* pscale  = (const float*)d_in[30];
    const float* head_w  = (const float*)d_in[31];
    const float* head_b  = (const float*)d_in[32];
    float* out = (float*)d_out;
    float* ws  = (float*)d_ws;

    const long NC = (long)NTOK * CDIM; // 1,048,576
    float* X0   = ws;            // [N,C]
    float* X1   = ws + NC;       // [N,C]
    float* RET  = ws + 2 * NC;   // [N,C]
    float* XCAT = ws + 3 * NC;   // [N,2C]
    float* QKV  = ws + 5 * NC;   // [N,3C]
    float* OUTS = ws + 8 * NC;   // [N,2C] phase outputs
    float* EN   = ws + 10 * NC;  // [N,256]
    float* SM   = ws + 10 * NC + NC / 2;  // small scratch
    float* PART = SM;                     // 16384
    float* HMEAN= SM + 16384;             // 1024
    float* AWARE= SM + 17408;             // 16 (padded)
    float* QUAL = SM + 17472;             // 2048
    float* WV   = SM + 19520;             // 4096
    int*   EIDX = (int*)(SM + 23616);     // 4096 ints
    // overlay region: prior [B,H,T,T] = 16*NC, reused post-attention
    float* R      = ws + 11 * NC;
    float* PRIOR  = R;
    float* Z      = R;
    float* XN     = R + NC;
    float* REASON = R + 2 * NC;
    float* INTRO  = R + 3 * NC;
    float* XQ     = R + 4 * NC;
    float* GATEB  = R + 5 * NC;
    float* EY     = R + 6 * NC;   // [N,2,C]
    float* EH     = R + 8 * NC;   // [N,2,HM]
    float* Q1B    = R + 12 * NC;  // [N,2048]

    auto gemm = [&](const float* A, int lda, const float* B, float* C_, int ldc,
                    const float* bias, const float* res, int ldres, float alpha,
                    int M, int Nn, int K, int transB, int act) {
        dim3 g(Nn / 64, M / 64);
        gemm_f32<<<g, dim3(256), 0, stream>>>(A, lda, B, C_, ldc, bias, res, ldres,
                                              alpha, M, Nn, K, transB, act);
    };

    // ---- embedding + memory bank ----
    embed_k<<<NTOK, 256, 0, stream>>>(ids, embed_w, X0);
    gemm(X0, CDIM, mem, EN, 256, nullptr, nullptr, 0, 1.f, NTOK, 256, CDIM, 1, 0);
    smrows_k<<<NTOK, 256, 0, stream>>>(EN);
    gemm(EN, 256, mem, RET, CDIM, nullptr, nullptr, 0, 1.f, NTOK, CDIM, 256, 0, 0);
    concat_k<<<4096, 256, 0, stream>>>(X0, RET, XCAT);
    gemm(XCAT, 1024, mp_w, X0, CDIM, mp_b, nullptr, 0, 1.f, NTOK, CDIM, 1024, 0, 0);

    float* xcur = X0;
    float* xalt = X1;
    for (int l = 0; l < 2; ++l) {
        // ---- two MetaCognitiveAttention phases ----
        for (int p = 0; p < 2; ++p) {
            const int lp = l * 2 + p;
            const float* hptr = (p == 0) ? xcur : OUTS;
            const int hlda = (p == 0) ? CDIM : 1024;
            gemm(hptr, hlda, qkv_w + (long)lp * CDIM * 1536, QKV, 1536,
                 qkv_b + (long)lp * 1536, nullptr, 0, 1.f, NTOK, 1536, CDIM, 0, 0);
            meanp_k<<<256, 64, 0, stream>>>(hptr, hlda, PART);
            meanr_k<<<4, 256, 0, stream>>>(PART, HMEAN);
            aware_k<<<1, 64, 0, stream>>>(HMEAN, aw_w, aw_b, lp, AWARE);
            attn_k<<<NB * NH * (TLEN / 8), 256, 0, stream>>>(
                QKV, dscale, lp, AWARE, PRIOR, (p == 1) ? 1 : 0, OUTS, 1024, p * CDIM);
        }
        // ---- merge + residual + LN ----
        gemm(OUTS, 1024, mg_w + (long)l * 1024 * CDIM, Z, CDIM, mg_b + (long)l * CDIM,
             xcur, CDIM, 1.f, NTOK, CDIM, 1024, 0, 0);
        ln_k<<<NTOK, 256, 0, stream>>>(Z, ln_g + (long)l * CDIM, ln_b + (long)l * CDIM, XN);
        // ---- MoE (top-2 sparse) ----
        gate_k<<<NTOK, 64, 0, stream>>>(XN, gw, gb, l, WV, EIDX);
        moe_eh_k<<<NTOK * 2, 256, 0, stream>>>(XN, EIDX, ew1, eb1, l, EH);
        moe_ey_k<<<NTOK * 2, 256, 0, stream>>>(EH, EIDX, ew2, eb2, l, EY);
        reason_k<<<4096, 256, 0, stream>>>(XN, EY, WV, REASON);
        // ---- introspection ----
        gemm(xcur, CDIM, q1w + (long)l * CDIM * 2048, Q1B, 2048, q1b + (long)l * 2048,
             nullptr, 0, 1.f, NTOK, 2048, CDIM, 0, 1 /*silu*/);
        qual_k<<<NTOK, 256, 0, stream>>>(Q1B, q2w, q2b, l, QUAL);
        xq_k<<<4096, 256, 0, stream>>>(xcur, QUAL, XQ);
        gemm(XQ, CDIM, errw + (long)l * CDIM * CDIM, INTRO, CDIM, errb + (long)l * CDIM,
             xcur, CDIM, 0.3f, NTOK, CDIM, CDIM, 0, 0);
        // ---- autonomous learning gate ----
        concat_k<<<4096, 256, 0, stream>>>(REASON, INTRO, XCAT);
        gemm(XCAT, 1024, ag1w, Q1B, 2048, ag1b, nullptr, 0, 1.f, NTOK, 2048, 1024, 0, 1);
        gemm(Q1B, 2048, ag2w, GATEB, CDIM, ag2b, nullptr, 0, 1.f, NTOK, CDIM, 2048, 0, 2);
        final_k<<<4096, 256, 0, stream>>>(REASON, GATEB, pscale, INTRO, xalt);
        float* tmp = xcur; xcur = xalt; xalt = tmp;
    }
    // ---- head ----
    gemm(xcur, CDIM, head_w, out, VDIM, head_b, nullptr, 0, 1.f, NTOK, VDIM, CDIM, 0, 0);
}

// Round 2
// 4732.779 us; speedup vs baseline: 1.4798x; 1.4798x over previous
//
#include <hip/hip_runtime.h>

// ConsciousTransformer forward. Round 2: all dense GEMMs via bf16 MFMA
// (m97 structure: 128x128 tile, BK=32, global_load_lds width=16, B in [N,K]).
// Dims: C=512, V=32000, L=2, P=2, E=8, HM=1024, H=8, M=256, B=2, T=1024, N=B*T=2048

#define NTOK 2048
#define CDIM 512
#define TLEN 1024
#define NB 2
#define NH 8
#define VDIM 32000

typedef __attribute__((ext_vector_type(4))) float f32x4;
typedef __attribute__((ext_vector_type(8))) __bf16 bf16x8;

#define AS1 __attribute__((address_space(1)))
#define AS3 __attribute__((address_space(3)))

__device__ __forceinline__ void g2lds16(const void* g, void* l) {
    __builtin_amdgcn_global_load_lds((const AS1 void*)g, (AS3 void*)l, 16, 0, 0);
}

// ---------------- bf16 MFMA GEMM: C = res + alpha*act(A@B^T + bias) ----------------
// A [M,K] bf16 packed, B [N,K] bf16 packed, C [M,N] fp32 (ldc).
// act: 0=none, 1=silu, 2=tanh. M,N mult of 128; K mult of 32.
__global__ __launch_bounds__(256) void gemm_bf16(
    const __bf16* __restrict__ A,
    const __bf16* __restrict__ B,
    float* __restrict__ C_, int ldc,
    const float* __restrict__ bias,
    const float* __restrict__ res, int ldres, float alpha,
    int K, int act)
{
    __shared__ __bf16 As[128 * 32];
    __shared__ __bf16 Bs[128 * 32];
    const int tid = threadIdx.x;
    const int w = tid >> 6, lane = tid & 63;
    const int m0 = blockIdx.y * 128, n0 = blockIdx.x * 128;
    const int wr = (w >> 1) * 64, wc = (w & 1) * 64;
    f32x4 acc[4][4] = {};
    const int mrow = lane & 15, kq = (lane >> 4) * 8;
    for (int k0 = 0; k0 < K; k0 += 32) {
#pragma unroll
        for (int i = 0; i < 2; ++i) {
            const int boff = w * 2048 + i * 1024 + lane * 16; // byte off in 128x32 bf16 tile
            const int row = boff >> 6;        // 64 B per row
            const int ke = (boff & 63) >> 1;  // bf16 elem within row
            g2lds16(A + (long)(m0 + row) * K + k0 + ke, (char*)As + (boff - lane * 16));
            g2lds16(B + (long)(n0 + row) * K + k0 + ke, (char*)Bs + (boff - lane * 16));
        }
        __syncthreads();
        bf16x8 af[4], bfr[4];
#pragma unroll
        for (int i = 0; i < 4; ++i)
            af[i] = *(const bf16x8*)(As + (wr + i * 16 + mrow) * 32 + kq);
#pragma unroll
        for (int j = 0; j < 4; ++j)
            bfr[j] = *(const bf16x8*)(Bs + (wc + j * 16 + mrow) * 32 + kq);
#pragma unroll
        for (int i = 0; i < 4; ++i)
#pragma unroll
            for (int j = 0; j < 4; ++j)
                acc[i][j] = __builtin_amdgcn_mfma_f32_16x16x32_bf16(af[i], bfr[j], acc[i][j], 0, 0, 0);
        __syncthreads();
    }
    const int col_l = lane & 15, row_l = (lane >> 4) * 4;
#pragma unroll
    for (int i = 0; i < 4; ++i)
#pragma unroll
        for (int j = 0; j < 4; ++j) {
            const int n = n0 + wc + j * 16 + col_l;
            const float bv = bias ? bias[n] : 0.f;
#pragma unroll
            for (int r = 0; r < 4; ++r) {
                const int m = m0 + wr + i * 16 + row_l + r;
                float v = acc[i][j][r] + bv;
                if (act == 1) v = v / (1.f + __expf(-v));
                else if (act == 2) v = tanhf(v);
                v *= alpha;
                if (res) v += res[(long)m * ldres + n];
                C_[(long)m * ldc + n] = v;
            }
        }
}

// ---------------- weight transpose+convert: W [K,N] f32 -> Wt [N,K] bf16 ----------------
__global__ __launch_bounds__(256) void wtrans_k(const float* __restrict__ W,
                                                __bf16* __restrict__ Wt, int K, int N)
{
    __shared__ float tile[64][65];
    const int k0 = blockIdx.y * 64, n0 = blockIdx.x * 64;
    const int t = threadIdx.x;
#pragma unroll
    for (int i = 0; i < 4; ++i) {
        const int r = (t >> 4) + i * 16;
        const int c = (t & 15) * 4;
        float4 v = *(const float4*)(W + (long)(k0 + r) * N + n0 + c);
        tile[r][c] = v.x; tile[r][c + 1] = v.y; tile[r][c + 2] = v.z; tile[r][c + 3] = v.w;
    }
    __syncthreads();
#pragma unroll
    for (int i = 0; i < 4; ++i) {
        const int rr = (t >> 4) + i * 16;   // n
        const int cc = (t & 15) * 4;        // k
        __bf16* o = Wt + (long)(n0 + rr) * K + k0 + cc;
        o[0] = (__bf16)tile[cc][rr];
        o[1] = (__bf16)tile[cc + 1][rr];
        o[2] = (__bf16)tile[cc + 2][rr];
        o[3] = (__bf16)tile[cc + 3][rr];
    }
}

// ---------------- activation convert: src [M,lda] f32 (first K cols) -> dst [M,K] bf16 ----------------
__global__ __launch_bounds__(256) void cvta_k(const float* __restrict__ src, int lda, int K,
                                              __bf16* __restrict__ dst)
{
    const int row = blockIdx.x, t = threadIdx.x;
    const float* s = src + (long)row * lda;
    __bf16* d = dst + (long)row * K;
    for (int c = t * 4; c < K; c += 1024) {
        float4 v = *(const float4*)(s + c);
        d[c] = (__bf16)v.x; d[c + 1] = (__bf16)v.y; d[c + 2] = (__bf16)v.z; d[c + 3] = (__bf16)v.w;
    }
}

// ---------------- embedding gather ----------------
__global__ __launch_bounds__(256) void embed_k(const int* __restrict__ ids,
                                               const float* __restrict__ ew,
                                               float* __restrict__ x)
{
    const int n = blockIdx.x, t = threadIdx.x;
    const long r = (long)ids[n] * CDIM;
    x[(long)n * CDIM + t]       = ew[r + t];
    x[(long)n * CDIM + 256 + t] = ew[r + 256 + t];
}

// ---------------- row softmax (width 256), in place ----------------
__global__ __launch_bounds__(256) void smrows_k(float* __restrict__ a)
{
    const int n = blockIdx.x, t = threadIdx.x;
    __shared__ float rs[256];
    float v = a[(long)n * 256 + t];
    rs[t] = v; __syncthreads();
    for (int o = 128; o; o >>= 1) { if (t < o) rs[t] = fmaxf(rs[t], rs[t + o]); __syncthreads(); }
    const float m = rs[0]; __syncthreads();
    const float e = __expf(v - m);
    rs[t] = e; __syncthreads();
    for (int o = 128; o; o >>= 1) { if (t < o) rs[t] += rs[t + o]; __syncthreads(); }
    a[(long)n * 256 + t] = e / rs[0];
}

// ---------------- concat two [N,C] -> [N,2C] ----------------
__global__ __launch_bounds__(256) void concat_k(const float* __restrict__ a,
                                                const float* __restrict__ b,
                                                float* __restrict__ o)
{
    const long i = (long)blockIdx.x * 256 + threadIdx.x;
    const long n = i >> 9;
    const int c = (int)(i & 511);
    o[n * 1024 + c]       = a[i];
    o[n * 1024 + 512 + c] = b[i];
}

// ---------------- mean over T (partial + reduce) ----------------
__global__ __launch_bounds__(64) void meanp_k(const float* __restrict__ A, int lda,
                                              float* __restrict__ part)
{
    const int bid = blockIdx.x;
    const int ts = bid & 15;
    const int cg = (bid >> 4) & 7;
    const int b  = bid >> 7;
    const int c  = cg * 64 + threadIdx.x;
    const float* p = A + ((long)b * TLEN + ts * 64) * lda + c;
    float s = 0.f;
    for (int t = 0; t < 64; ++t) s += p[(long)t * lda];
    part[(long)ts * 1024 + b * 512 + c] = s;
}
__global__ __launch_bounds__(256) void meanr_k(const float* __restrict__ part,
                                               float* __restrict__ hm)
{
    const int i = blockIdx.x * 256 + threadIdx.x;
    float s = 0.f;
    for (int ts = 0; ts < 16; ++ts) s += part[ts * 1024 + i];
    hm[i] = s * (1.f / 1024.f);
}

// ---------------- awareness ----------------
__global__ __launch_bounds__(64) void aware_k(const float* __restrict__ hm,
                                              const float* __restrict__ aw_w,
                                              const float* __restrict__ aw_b,
                                              int lp, float* __restrict__ out)
{
    const int t = threadIdx.x;
    if (t < NB * NH) {
        const int b = t >> 3, hh = t & 7;
        const float* W = aw_w + (long)lp * CDIM * NH;
        const float* x = hm + b * CDIM;
        float s = aw_b[lp * NH + hh];
        for (int c = 0; c < CDIM; ++c) s += x[c] * W[c * NH + hh];
        out[t] = s;
    }
}

// ---------------- fused attention (8 rows per block) ----------------
__global__ __launch_bounds__(256) void attn_k(
    const float* __restrict__ qkv,
    const float* __restrict__ dscale, int lp,
    const float* __restrict__ aware,
    float* __restrict__ prior,
    int use_prior,
    float* __restrict__ outs, int ldouts, int out_off)
{
    const int tid = threadIdx.x;
    const int rblk = blockIdx.x % (TLEN / 8);
    const int bh = blockIdx.x / (TLEN / 8);
    const int b = bh / NH, h = bh % NH;
    const int t0 = rblk * 8;
    __shared__ float qs[8][64];
    __shared__ float kt[64][68];
    __shared__ float ss[8][1024];
    __shared__ float rinv[8];
    const float scale = dscale[lp] * aware[bh];
    for (int i = tid; i < 512; i += 256) {
        const int r = i >> 6, d = i & 63;
        qs[r][d] = qkv[(long)(b * TLEN + t0 + r) * 1536 + h * 64 + d] * scale;
    }
    __syncthreads();
    for (int s0 = 0; s0 < TLEN; s0 += 64) {
        for (int i = tid; i < 4096; i += 256) {
            const int sr = i >> 6, d = i & 63;
            kt[sr][d] = qkv[(long)(b * TLEN + s0 + sr) * 1536 + 512 + h * 64 + d];
        }
        __syncthreads();
        for (int i = tid; i < 512; i += 256) {
            const int r = i >> 6, c = i & 63;
            float acc = 0.f;
#pragma unroll
            for (int d = 0; d < 64; d += 4) {
                const float4 qv = *(const float4*)&qs[r][d];
                const float4 kv = *(const float4*)&kt[c][d];
                acc += qv.x * kv.x + qv.y * kv.y + qv.z * kv.z + qv.w * kv.w;
            }
            ss[r][s0 + c] = acc;
        }
        __syncthreads();
    }
    {
        const int r = tid >> 5, lane = tid & 31;
        float m = -1e30f;
        for (int c = lane; c < TLEN; c += 32) m = fmaxf(m, ss[r][c]);
        for (int o = 16; o; o >>= 1) m = fmaxf(m, __shfl_down(m, o, 32));
        m = __shfl(m, 0, 32);
        float sum = 0.f;
        for (int c = lane; c < TLEN; c += 32) {
            const float e = __expf(ss[r][c] - m);
            ss[r][c] = e;
            sum += e;
        }
        for (int o = 16; o; o >>= 1) sum += __shfl_down(sum, o, 32);
        if (lane == 0) rinv[r] = 1.f / sum;
    }
    __syncthreads();
    {
        const long pbase = ((long)bh * TLEN + t0) * TLEN;
        for (int i = tid; i < 8 * TLEN; i += 256) {
            const int r = i >> 10, c = i & 1023;
            float v = ss[r][c] * rinv[r];
            if (use_prior) v += 0.3f * prior[pbase + (long)r * TLEN + c];
            ss[r][c] = v;
            prior[pbase + (long)r * TLEN + c] = v;
        }
    }
    __syncthreads();
    float oacc0 = 0.f, oacc1 = 0.f;
    for (int s0 = 0; s0 < TLEN; s0 += 64) {
        for (int i = tid; i < 4096; i += 256) {
            const int sr = i >> 6, d = i & 63;
            kt[sr][d] = qkv[(long)(b * TLEN + s0 + sr) * 1536 + 1024 + h * 64 + d];
        }
        __syncthreads();
        {
            const int r0 = tid >> 6, d0 = tid & 63;
            const int r1 = (tid + 256) >> 6, d1 = (tid + 256) & 63;
            float a0 = 0.f, a1 = 0.f;
#pragma unroll
            for (int sr = 0; sr < 64; ++sr) {
                a0 += ss[r0][s0 + sr] * kt[sr][d0];
                a1 += ss[r1][s0 + sr] * kt[sr][d1];
            }
            oacc0 += a0; oacc1 += a1;
        }
        __syncthreads();
    }
    {
        const int r0 = tid >> 6, d0 = tid & 63;
        const int r1 = (tid + 256) >> 6, d1 = (tid + 256) & 63;
        float v0 = oacc0 / (1.f + __expf(-oacc0));
        float v1 = oacc1 / (1.f + __expf(-oacc1));
        outs[(long)(b * TLEN + t0 + r0) * ldouts + out_off + h * 64 + d0] = v0;
        outs[(long)(b * TLEN + t0 + r1) * ldouts + out_off + h * 64 + d1] = v1;
    }
}

// ---------------- layernorm over C=512 ----------------
__global__ __launch_bounds__(256) void ln_k(const float* __restrict__ z,
                                            const float* __restrict__ g,
                                            const float* __restrict__ bb,
                                            float* __restrict__ xn)
{
    const int n = blockIdx.x, t = threadIdx.x;
    __shared__ float rs[256], rq[256];
    const float v0 = z[(long)n * 512 + t];
    const float v1 = z[(long)n * 512 + 256 + t];
    rs[t] = v0 + v1;
    rq[t] = v0 * v0 + v1 * v1;
    __syncthreads();
    for (int o = 128; o; o >>= 1) {
        if (t < o) { rs[t] += rs[t + o]; rq[t] += rq[t + o]; }
        __syncthreads();
    }
    const float mu = rs[0] * (1.f / 512.f);
    const float var = rq[0] * (1.f / 512.f) - mu * mu;
    const float rstd = rsqrtf(var + 1e-5f);
    xn[(long)n * 512 + t]       = (v0 - mu) * rstd * g[t] + bb[t];
    xn[(long)n * 512 + 256 + t] = (v1 - mu) * rstd * g[t + 256] + bb[t + 256];
}

// ---------------- MoE gate ----------------
__global__ __launch_bounds__(64) void gate_k(const float* __restrict__ xn,
                                             const float* __restrict__ gw,
                                             const float* __restrict__ gb,
                                             int l, float* __restrict__ wv,
                                             int* __restrict__ eidx)
{
    const int n = blockIdx.x, t = threadIdx.x;
    const int e = t & 7, ch = t >> 3;
    const float* W = gw + (long)l * CDIM * 8;
    float part = 0.f;
    for (int k = ch * 64; k < ch * 64 + 64; ++k) part += xn[(long)n * CDIM + k] * W[k * 8 + e];
    part += __shfl_xor(part, 8, 64);
    part += __shfl_xor(part, 16, 64);
    part += __shfl_xor(part, 32, 64);
    __shared__ float lg[8];
    if (t < 8) lg[t] = part + gb[l * 8 + t];
    __syncthreads();
    if (t == 0) {
        float m = lg[0];
        for (int i = 1; i < 8; ++i) m = fmaxf(m, lg[i]);
        float p[8], s = 0.f;
        for (int i = 0; i < 8; ++i) { p[i] = __expf(lg[i] - m); s += p[i]; }
        const float inv = 1.f / s;
        int i0 = 0;
        for (int i = 1; i < 8; ++i) if (p[i] > p[i0]) i0 = i;
        int i1 = (i0 == 0) ? 1 : 0;
        for (int i = 0; i < 8; ++i) { if (i == i0) continue; if (p[i] > p[i1]) i1 = i; }
        eidx[n * 2] = i0; eidx[n * 2 + 1] = i1;
        wv[n * 2] = p[i0] * inv; wv[n * 2 + 1] = p[i1] * inv;
    }
}

// ---------------- MoE expert mlp1 ----------------
__global__ __launch_bounds__(256) void moe_eh_k(const float* __restrict__ xn,
                                                const int* __restrict__ eidx,
                                                const float* __restrict__ ew1,
                                                const float* __restrict__ eb1,
                                                int l, float* __restrict__ eh)
{
    const int ns = blockIdx.x, n = ns >> 1, slot = ns & 1;
    const int e = eidx[n * 2 + slot];
    const float* W = ew1 + (long)(l * 8 + e) * CDIM * 1024;
    const float* bb = eb1 + (long)(l * 8 + e) * 1024;
    __shared__ float xs[CDIM];
    const int t = threadIdx.x;
    xs[t] = xn[(long)n * CDIM + t];
    xs[t + 256] = xn[(long)n * CDIM + 256 + t];
    __syncthreads();
    float acc[4];
#pragma unroll
    for (int j = 0; j < 4; ++j) acc[j] = bb[t + 256 * j];
    for (int k = 0; k < CDIM; ++k) {
        const float xv = xs[k];
        const float* Wr = W + (long)k * 1024;
#pragma unroll
        for (int j = 0; j < 4; ++j) acc[j] += xv * Wr[t + 256 * j];
    }
#pragma unroll
    for (int j = 0; j < 4; ++j) {
        const float a = acc[j];
        eh[(long)ns * 1024 + t + 256 * j] = a * a / (1.f + __expf(-a));
    }
}

// ---------------- MoE expert mlp2 ----------------
__global__ __launch_bounds__(256) void moe_ey_k(const float* __restrict__ eh,
                                                const int* __restrict__ eidx,
                                                const float* __restrict__ ew2,
                                                const float* __restrict__ eb2,
                                                int l, float* __restrict__ ey)
{
    const int ns = blockIdx.x, n = ns >> 1, slot = ns & 1;
    const int e = eidx[n * 2 + slot];
    const float* W = ew2 + (long)(l * 8 + e) * 1024 * CDIM;
    const float* bb = eb2 + (long)(l * 8 + e) * CDIM;
    __shared__ float xs[1024];
    const int t = threadIdx.x;
    for (int i = t; i < 1024; i += 256) xs[i] = eh[(long)ns * 1024 + i];
    __syncthreads();
    float a0 = bb[t], a1 = bb[t + 256];
    for (int k = 0; k < 1024; ++k) {
        const float xv = xs[k];
        a0 += xv * W[(long)k * CDIM + t];
        a1 += xv * W[(long)k * CDIM + t + 256];
    }
    ey[(long)ns * CDIM + t] = a0;
    ey[(long)ns * CDIM + t + 256] = a1;
}

// ---------------- reason = xn + 0.5*(w0*ey0 + w1*ey1) ----------------
__global__ __launch_bounds__(256) void reason_k(const float* __restrict__ xn,
                                                const float* __restrict__ ey,
                                                const float* __restrict__ wv,
                                                float* __restrict__ reason)
{
    const long i = (long)blockIdx.x * 256 + threadIdx.x;
    const long n = i >> 9;
    const int c = (int)(i & 511);
    const float v = wv[n * 2] * ey[n * 1024 + c] + wv[n * 2 + 1] * ey[n * 1024 + 512 + c];
    reason[i] = xn[i] + 0.5f * v;
}

// ---------------- quality ----------------
__global__ __launch_bounds__(256) void qual_k(const float* __restrict__ t1,
                                              const float* __restrict__ q2w,
                                              const float* __restrict__ q2b,
                                              int l, float* __restrict__ qual)
{
    const int n = blockIdx.x, t = threadIdx.x;
    const float* W = q2w + (long)l * 2048;
    float s = 0.f;
    for (int k = t; k < 2048; k += 256) s += t1[(long)n * 2048 + k] * W[k];
    __shared__ float rs[256];
    rs[t] = s; __syncthreads();
    for (int o = 128; o; o >>= 1) { if (t < o) rs[t] += rs[t + o]; __syncthreads(); }
    if (t == 0) {
        const float q = rs[0] + q2b[l];
        qual[n] = 1.f / (1.f + __expf(-q));
    }
}

// ---------------- xq = x_in * (1 - quality) ----------------
__global__ __launch_bounds__(256) void xq_k(const float* __restrict__ x_in,
                                            const float* __restrict__ qual,
                                            float* __restrict__ xq)
{
    const long i = (long)blockIdx.x * 256 + threadIdx.x;
    const long n = i >> 9;
    xq[i] = x_in[i] * (1.f - qual[n]);
}

// ---------------- x = reason + gate*pscale*intro ----------------
__global__ __launch_bounds__(256) void final_k(const float* __restrict__ reason,
                                               const float* __restrict__ gate,
                                               const float* __restrict__ pscale,
                                               const float* __restrict__ intro,
                                               float* __restrict__ xo)
{
    const long i = (long)blockIdx.x * 256 + threadIdx.x;
    const int c = (int)(i & 511);
    xo[i] = reason[i] + gate[i] * pscale[c] * intro[i];
}

// =======================================================================
extern "C" void kernel_launch(void* const* d_in, const int* in_sizes, int n_in,
                              void* d_out, int out_size, void* d_ws, size_t ws_size,
                              hipStream_t stream)
{
    (void)in_sizes; (void)n_in; (void)out_size; (void)ws_size;
    const int*   ids     = (const int*)  d_in[0];
    const float* embed_w = (const float*)d_in[1];
    const float* mem     = (const float*)d_in[2];
    const float* mp_w    = (const float*)d_in[3];
    const float* mp_b    = (const float*)d_in[4];
    const float* qkv_w   = (const float*)d_in[5];
    const float* qkv_b   = (const float*)d_in[6];
    const float* aw_w    = (const float*)d_in[7];
    const float* aw_b    = (const float*)d_in[8];
    const float* dscale  = (const float*)d_in[9];
    const float* mg_w    = (const float*)d_in[10];
    const float* mg_b    = (const float*)d_in[11];
    const float* ln_g    = (const float*)d_in[12];
    const float* ln_b    = (const float*)d_in[13];
    const float* gw      = (const float*)d_in[14];
    const float* gb      = (const float*)d_in[15];
    const float* ew1     = (const float*)d_in[16];
    const float* eb1     = (const float*)d_in[17];
    const float* ew2     = (const float*)d_in[18];
    const float* eb2     = (const float*)d_in[19];
    const float* q1w     = (const float*)d_in[20];
    const float* q1b     = (const float*)d_in[21];
    const float* q2w     = (const float*)d_in[22];
    const float* q2b     = (const float*)d_in[23];
    const float* errw    = (const float*)d_in[24];
    const float* errb    = (const float*)d_in[25];
    const float* ag1w    = (const float*)d_in[26];
    const float* ag1b    = (const float*)d_in[27];
    const float* ag2w    = (const float*)d_in[28];
    const float* ag2b    = (const float*)d_in[29];
    const float* pscale  = (const float*)d_in[30];
    const float* head_w  = (const float*)d_in[31];
    const float* head_b  = (const float*)d_in[32];
    float* out = (float*)d_out;
    float* ws  = (float*)d_ws;

    const long NC = (long)NTOK * CDIM; // 1,048,576
    float* X0   = ws;
    float* X1   = ws + NC;
    float* RET  = ws + 2 * NC;
    float* XCAT = ws + 3 * NC;       // [N,2C]
    float* QKV  = ws + 5 * NC;       // [N,3C]
    float* OUTS = ws + 8 * NC;       // [N,2C]
    float* EN   = ws + 10 * NC;      // [N,256]
    float* SM   = ws + 10 * NC + NC / 2;
    float* PART = SM;
    float* HMEAN= SM + 16384;
    float* AWARE= SM + 17408;
    float* QUAL = SM + 17472;
    float* WV   = SM + 19520;
    int*   EIDX = (int*)(SM + 23616);
    float* R      = ws + 11 * NC;    // overlay: prior [B,H,T,T] = 16*NC
    float* PRIOR  = R;
    float* Z      = R;
    float* XN     = R + NC;
    float* REASON = R + 2 * NC;
    float* INTRO  = R + 3 * NC;
    float* XQ     = R + 4 * NC;
    float* GATEB  = R + 5 * NC;
    float* EY     = R + 6 * NC;
    float* EH     = R + 8 * NC;
    float* Q1B    = R + 12 * NC;     // [N,2048]

    // bf16 region after 27*NC floats
    __bf16* bfw = (__bf16*)(ws + 27 * NC);
    __bf16* WB_mp   = bfw;                       // 512*1024
    __bf16* WB_qkv  = bfw + 524288;              // 4 * 1536*512
    __bf16* WB_mg   = bfw + 3670016;             // 2 * 512*1024
    __bf16* WB_q1   = bfw + 4718592;             // 2 * 2048*512
    __bf16* WB_err  = bfw + 6815744;             // 2 * 512*512
    __bf16* WB_ag1  = bfw + 7340032;             // 2048*1024
    __bf16* WB_ag2  = bfw + 9437184;             // 512*2048
    __bf16* WB_memn = bfw + 10485760;            // 256*512
    __bf16* WB_memt = bfw + 10616832;            // 512*256
    __bf16* WB_head = bfw + 10747904;            // 32000*512
    __bf16* ABF     = bfw + 27131904;            // up to 2048*2048

    auto wtrans = [&](const float* W, __bf16* Wt, int K, int N) {
        wtrans_k<<<dim3(N / 64, K / 64), 256, 0, stream>>>(W, Wt, K, N);
    };
    auto gemm = [&](const float* Asrc, int lda, const __bf16* B, float* C_, int ldc,
                    const float* bias, const float* res, int ldres, float alpha,
                    int Nn, int K, int act) {
        cvta_k<<<NTOK, 256, 0, stream>>>(Asrc, lda, K, ABF);
        gemm_bf16<<<dim3(Nn / 128, NTOK / 128), 256, 0, stream>>>(
            ABF, B, C_, ldc, bias, res, ldres, alpha, K, act);
    };

    // ---- weight conversion (same work every call; graph-safe) ----
    wtrans(mp_w, WB_mp, 1024, 512);
    for (int lp = 0; lp < 4; ++lp)
        wtrans(qkv_w + (long)lp * 512 * 1536, WB_qkv + (long)lp * 1536 * 512, 512, 1536);
    for (int l = 0; l < 2; ++l) {
        wtrans(mg_w + (long)l * 1024 * 512, WB_mg + (long)l * 512 * 1024, 1024, 512);
        wtrans(q1w + (long)l * 512 * 2048, WB_q1 + (long)l * 2048 * 512, 512, 2048);
        wtrans(errw + (long)l * 512 * 512, WB_err + (long)l * 512 * 512, 512, 512);
    }
    wtrans(ag1w, WB_ag1, 1024, 2048);
    wtrans(ag2w, WB_ag2, 2048, 512);
    wtrans(head_w, WB_head, 512, VDIM);
    wtrans(mem, WB_memt, 256, 512);                     // mem^T [512,256]
    cvta_k<<<256, 256, 0, stream>>>(mem, 512, 512, WB_memn); // mem [256,512] as [N,K]

    // ---- embedding + memory bank ----
    embed_k<<<NTOK, 256, 0, stream>>>(ids, embed_w, X0);
    gemm(X0, 512, WB_memn, EN, 256, nullptr, nullptr, 0, 1.f, 256, 512, 0);
    smrows_k<<<NTOK, 256, 0, stream>>>(EN);
    gemm(EN, 256, WB_memt, RET, 512, nullptr, nullptr, 0, 1.f, 512, 256, 0);
    concat_k<<<4096, 256, 0, stream>>>(X0, RET, XCAT);
    gemm(XCAT, 1024, WB_mp, X0, 512, mp_b, nullptr, 0, 1.f, 512, 1024, 0);

    float* xcur = X0;
    float* xalt = X1;
    for (int l = 0; l < 2; ++l) {
        for (int p = 0; p < 2; ++p) {
            const int lp = l * 2 + p;
            const float* hptr = (p == 0) ? xcur : OUTS;
            const int hlda = (p == 0) ? 512 : 1024;
            gemm(hptr, hlda, WB_qkv + (long)lp * 1536 * 512, QKV, 1536,
                 qkv_b + (long)lp * 1536, nullptr, 0, 1.f, 1536, 512, 0);
            meanp_k<<<256, 64, 0, stream>>>(hptr, hlda, PART);
            meanr_k<<<4, 256, 0, stream>>>(PART, HMEAN);
            aware_k<<<1, 64, 0, stream>>>(HMEAN, aw_w, aw_b, lp, AWARE);
            attn_k<<<NB * NH * (TLEN / 8), 256, 0, stream>>>(
                QKV, dscale, lp, AWARE, PRIOR, (p == 1) ? 1 : 0, OUTS, 1024, p * CDIM);
        }
        gemm(OUTS, 1024, WB_mg + (long)l * 512 * 1024, Z, 512, mg_b + (long)l * 512,
             xcur, 512, 1.f, 512, 1024, 0);
        ln_k<<<NTOK, 256, 0, stream>>>(Z, ln_g + (long)l * 512, ln_b + (long)l * 512, XN);
        gate_k<<<NTOK, 64, 0, stream>>>(XN, gw, gb, l, WV, EIDX);
        moe_eh_k<<<NTOK * 2, 256, 0, stream>>>(XN, EIDX, ew1, eb1, l, EH);
        moe_ey_k<<<NTOK * 2, 256, 0, stream>>>(EH, EIDX, ew2, eb2, l, EY);
        reason_k<<<4096, 256, 0, stream>>>(XN, EY, WV, REASON);
        gemm(xcur, 512, WB_q1 + (long)l * 2048 * 512, Q1B, 2048, q1b + (long)l * 2048,
             nullptr, 0, 1.f, 2048, 512, 1);
        qual_k<<<NTOK, 256, 0, stream>>>(Q1B, q2w, q2b, l, QUAL);
        xq_k<<<4096, 256, 0, stream>>>(xcur, QUAL, XQ);
        gemm(XQ, 512, WB_err + (long)l * 512 * 512, INTRO, 512, errb + (long)l * 512,
             xcur, 512, 0.3f, 512, 512, 0);
        concat_k<<<4096, 256, 0, stream>>>(REASON, INTRO, XCAT);
        gemm(XCAT, 1024, WB_ag1, Q1B, 2048, ag1b, nullptr, 0, 1.f, 2048, 1024, 1);
        gemm(Q1B, 2048, WB_ag2, GATEB, 512, ag2b, nullptr, 0, 1.f, 512, 2048, 2);
        final_k<<<4096, 256, 0, stream>>>(REASON, GATEB, pscale, INTRO, xalt);
        float* tmp = xcur; xcur = xalt; xalt = tmp;
    }
    // ---- head ----
    gemm(xcur, 512, WB_head, out, VDIM, head_b, nullptr, 0, 1.f, VDIM, 512, 0);
}